// Round 2
// baseline (244.151 us; speedup 1.0000x reference)
//
#include <hip/hip_runtime.h>
#include <hip/hip_bf16.h>

#define NN 2048

typedef __attribute__((ext_vector_type(8))) short short8;
typedef __attribute__((ext_vector_type(8))) unsigned short ushort8;
typedef __attribute__((ext_vector_type(4))) float f32x4;

__device__ __forceinline__ unsigned short f2bf(float f) {
    unsigned int u = __float_as_uint(f);
    u += 0x7fffu + ((u >> 16) & 1u);   // RNE; inputs are squares, no NaN/Inf
    return (unsigned short)(u >> 16);
}

// ---------------------------------------------------------------------------
// K1: B = A0*A0 elementwise -> bf16 row-major (Bbf) and bf16 transposed (BbfT)
// ---------------------------------------------------------------------------
__global__ void prep_kernel(const float* __restrict__ A0,
                            unsigned short* __restrict__ Bbf,
                            unsigned short* __restrict__ BbfT) {
    __shared__ float tile[32][33];
    const int tx = threadIdx.x, ty = threadIdx.y;
    const int I = blockIdx.y, J = blockIdx.x;
    #pragma unroll
    for (int rr = ty; rr < 32; rr += 8) {
        float a = A0[(size_t)(I * 32 + rr) * NN + J * 32 + tx];
        float s = a * a;
        tile[rr][tx] = s;
        Bbf[(size_t)(I * 32 + rr) * NN + J * 32 + tx] = f2bf(s);
    }
    __syncthreads();
    #pragma unroll
    for (int rr = ty; rr < 32; rr += 8) {
        BbfT[(size_t)(J * 32 + rr) * NN + I * 32 + tx] = f2bf(tile[tx][rr]);
    }
}

// ---------------------------------------------------------------------------
// K2: C2 = B * B  (bf16 MFMA, fp32 accum). A = Bbf rows, BT = BbfT rows.
// 128x128 tile, 4 waves (2x2), each wave 64x64 = 4x4 fragments of 16x16x32.
// ---------------------------------------------------------------------------
__launch_bounds__(256, 2)
__global__ void gemm_kernel(const unsigned short* __restrict__ A,
                            const unsigned short* __restrict__ BT,
                            float* __restrict__ C) {
    __shared__ unsigned short lA[128 * 32];
    __shared__ unsigned short lB[128 * 32];
    const int tid  = threadIdx.x;
    const int lane = tid & 63;
    const int w    = tid >> 6;
    const int wr   = w >> 1, wc = w & 1;
    const int rowBase = blockIdx.y * 128;
    const int colBase = blockIdx.x * 128;
    const int lr = lane & 15;            // M/N index within fragment
    const int lk = (lane >> 4) * 8;      // K offset (elements)

    f32x4 acc[4][4] = {};

    for (int k0 = 0; k0 < NN; k0 += 32) {
        // stage 128x32 bf16 tiles of A and BT into LDS (reg-staged, 16B/thread/issue)
        #pragma unroll
        for (int iss = 0; iss < 2; ++iss) {
            int off  = iss * 4096 + tid * 16;   // byte offset within 8KB tile
            int row  = off >> 6;                // 64 B per row (32 bf16)
            int kcol = (off & 63) >> 1;         // element offset within row
            ushort8 va = *(const ushort8*)(A  + (size_t)(rowBase + row) * NN + k0 + kcol);
            ushort8 vb = *(const ushort8*)(BT + (size_t)(colBase + row) * NN + k0 + kcol);
            *(ushort8*)&lA[row * 32 + kcol] = va;
            *(ushort8*)&lB[row * 32 + kcol] = vb;
        }
        __syncthreads();

        short8 af[4], bfr[4];
        #pragma unroll
        for (int mi = 0; mi < 4; ++mi)
            af[mi] = *(const short8*)&lA[(wr * 64 + mi * 16 + lr) * 32 + lk];
        #pragma unroll
        for (int ni = 0; ni < 4; ++ni)
            bfr[ni] = *(const short8*)&lB[(wc * 64 + ni * 16 + lr) * 32 + lk];

        #pragma unroll
        for (int mi = 0; mi < 4; ++mi)
            #pragma unroll
            for (int ni = 0; ni < 4; ++ni)
                acc[mi][ni] = __builtin_amdgcn_mfma_f32_16x16x32_bf16(
                    af[mi], bfr[ni], acc[mi][ni], 0, 0, 0);
        __syncthreads();
    }

    // C/D layout: col = lane&15, row = (lane>>4)*4 + reg   [measured m89/m91]
    const int orow = (lane >> 4) * 4;
    const int ocol = lane & 15;
    #pragma unroll
    for (int mi = 0; mi < 4; ++mi)
        #pragma unroll
        for (int ni = 0; ni < 4; ++ni) {
            int gr = rowBase + wr * 64 + mi * 16 + orow;
            int gc = colBase + wc * 64 + ni * 16 + ocol;
            #pragma unroll
            for (int r = 0; r < 4; ++r)
                C[(size_t)(gr + r) * NN + gc] = acc[mi][ni][r];
        }
}

// ---------------------------------------------------------------------------
// K3: t2 = <B,B^T>, t3 = <C2,B^T>, t4 = <C2,C2^T> over 32x32 tile-pairs
// ---------------------------------------------------------------------------
__global__ void reduce_pairs_kernel(const float* __restrict__ A0,
                                    const float* __restrict__ C2,
                                    double* __restrict__ accs) {
    __shared__ float aIJ[32][33], aJI[32][33], cIJ[32][33], cJI[32][33];
    __shared__ double red[256];
    int b = blockIdx.x;
    int I = 0;
    while (b >= 64 - I) { b -= 64 - I; ++I; }   // map to upper-tri pair (I<=J)
    const int J  = I + b;
    const int tx = threadIdx.x, ty = threadIdx.y;
    const int t  = ty * 32 + tx;
    const size_t rI = (size_t)I * 32, rJ = (size_t)J * 32;

    for (int rr = ty; rr < 32; rr += 8) {
        float aij = A0[(rI + rr) * NN + rJ + tx];
        float aji = A0[(rJ + rr) * NN + rI + tx];
        aIJ[rr][tx] = aij * aij;
        aJI[rr][tx] = aji * aji;
        cIJ[rr][tx] = C2[(rI + rr) * NN + rJ + tx];
        cJI[rr][tx] = C2[(rJ + rr) * NN + rI + tx];
    }
    __syncthreads();

    double t2c = 0, t3c = 0, t4c = 0;
    for (int rr = ty; rr < 32; rr += 8) {
        float bij = aIJ[rr][tx], bji = aJI[tx][rr];
        float cij = cIJ[rr][tx], cji = cJI[tx][rr];
        if (I == J) {
            t2c += (double)bij * bji;
            t3c += (double)cij * bji;
            t4c += (double)cij * cji;
        } else {
            t2c += 2.0 * (double)bij * bji;
            t3c += (double)cij * bji + (double)cji * bij;
            t4c += 2.0 * (double)cij * cji;
        }
    }

    red[t] = t2c; __syncthreads();
    for (int s = 128; s > 0; s >>= 1) { if (t < s) red[t] += red[t + s]; __syncthreads(); }
    if (t == 0) atomicAdd(&accs[0], red[0]);
    __syncthreads();
    red[t] = t3c; __syncthreads();
    for (int s = 128; s > 0; s >>= 1) { if (t < s) red[t] += red[t + s]; __syncthreads(); }
    if (t == 0) atomicAdd(&accs[1], red[0]);
    __syncthreads();
    red[t] = t4c; __syncthreads();
    for (int s = 128; s > 0; s >>= 1) { if (t < s) red[t] += red[t + s]; __syncthreads(); }
    if (t == 0) atomicAdd(&accs[2], red[0]);
}

// ---------------------------------------------------------------------------
// K4a/K4b: row sums and column sums of C2 (for lambda1^2 = 1'B^4 1 / 1'B^2 1)
// ---------------------------------------------------------------------------
__global__ void rowsum_kernel(const float* __restrict__ C2, float* __restrict__ rs) {
    __shared__ float red[256];
    const int i = blockIdx.x, t = threadIdx.x;
    float s = 0;
    for (int j = t; j < NN; j += 256) s += C2[(size_t)i * NN + j];
    red[t] = s; __syncthreads();
    for (int k = 128; k > 0; k >>= 1) { if (t < k) red[t] += red[t + k]; __syncthreads(); }
    if (t == 0) rs[i] = red[0];
}

__global__ void colsum_kernel(const float* __restrict__ C2, float* __restrict__ cs) {
    const int j  = (blockIdx.x & 7) * 256 + threadIdx.x;
    const int i0 = (blockIdx.x >> 3) * 64;   // 32 slabs of 64 rows
    float s = 0;
    for (int i = i0; i < i0 + 64; ++i) s += C2[(size_t)i * NN + j];
    atomicAdd(&cs[j], s);
}

// ---------------------------------------------------------------------------
// K5: t1 = tr(B); lam1^2 = s4/s2; h = t1 + t2/2 + t3/6 + t4/24 + rank-1 tail
// ---------------------------------------------------------------------------
__global__ void finalize_kernel(const float* __restrict__ A0,
                                const float* __restrict__ rs,
                                const float* __restrict__ cs,
                                const double* __restrict__ accs,
                                float* __restrict__ out) {
    __shared__ double red[256];
    const int t = threadIdx.x;
    double t1 = 0, s2 = 0, s4 = 0;
    for (int i = t; i < NN; i += 256) {
        double d = A0[(size_t)i * NN + i];
        t1 += d * d;
        double r = rs[i], c = cs[i];
        s2 += r; s4 += r * c;
    }
    red[t] = t1; __syncthreads();
    for (int s = 128; s > 0; s >>= 1) { if (t < s) red[t] += red[t + s]; __syncthreads(); }
    double T1 = red[0]; __syncthreads();
    red[t] = s2; __syncthreads();
    for (int s = 128; s > 0; s >>= 1) { if (t < s) red[t] += red[t + s]; __syncthreads(); }
    double S2 = red[0]; __syncthreads();
    red[t] = s4; __syncthreads();
    for (int s = 128; s > 0; s >>= 1) { if (t < s) red[t] += red[t + s]; __syncthreads(); }
    double S4 = red[0];

    if (t == 0) {
        double t2 = accs[0], t3 = accs[1], t4 = accs[2];
        double lam2 = S4 / S2;
        double lam  = sqrt(lam2);
        // tail = sum_{k>=5} lam^k / k!
        double tail = exp(lam) - 1.0 - lam - lam2 * 0.5
                      - lam * lam2 * (1.0 / 6.0) - lam2 * lam2 * (1.0 / 24.0);
        double h = T1 + t2 * 0.5 + t3 * (1.0 / 6.0) + t4 * (1.0 / 24.0) + tail;
        out[0] = (float)h;
    }
}

// ---------------------------------------------------------------------------
extern "C" void kernel_launch(void* const* d_in, const int* in_sizes, int n_in,
                              void* d_out, int out_size, void* d_ws, size_t ws_size,
                              hipStream_t stream) {
    const float* A0 = (const float*)d_in[0];     // contemporaneous slice [2048,2048]
    char* ws = (char*)d_ws;
    // ws layout (33.6 MB total):
    unsigned short* Bbf  = (unsigned short*)(ws);                 //  8 MB bf16 B
    unsigned short* BbfT = (unsigned short*)(ws + 8388608);       //  8 MB bf16 B^T
    float*  C2   = (float*)(ws + 16777216);                       // 16 MB fp32 B^2
    float*  rs   = (float*)(ws + 33554432);                       //  8 KB rowsums
    float*  cs   = (float*)(ws + 33562624);                       //  8 KB colsums
    double* accs = (double*)(ws + 33570816);                      //  t2,t3,t4
    float*  out  = (float*)d_out;

    prep_kernel<<<dim3(64, 64), dim3(32, 8), 0, stream>>>(A0, Bbf, BbfT);
    gemm_kernel<<<dim3(16, 16), 256, 0, stream>>>(Bbf, BbfT, C2);
    hipMemsetAsync(ws + 33562624, 0, 8192 + 32, stream);          // cs + accs
    reduce_pairs_kernel<<<2080, dim3(32, 8), 0, stream>>>(A0, C2, accs);
    rowsum_kernel<<<2048, 256, 0, stream>>>(C2, rs);
    colsum_kernel<<<256, 256, 0, stream>>>(C2, cs);
    finalize_kernel<<<1, 256, 0, stream>>>(A0, rs, cs, accs, out);
}

// Round 3
// 169.395 us; speedup vs baseline: 1.4413x; 1.4413x over previous
//
#include <hip/hip_runtime.h>
#include <hip/hip_bf16.h>

#define NN 2048

typedef __attribute__((ext_vector_type(8))) short short8;
typedef __attribute__((ext_vector_type(8))) unsigned short ushort8;
typedef __attribute__((ext_vector_type(4))) float f32x4;
typedef __attribute__((ext_vector_type(4))) float f4;

__device__ __forceinline__ unsigned short f2bf(float f) {
    unsigned int u = __float_as_uint(f);
    u += 0x7fffu + ((u >> 16) & 1u);   // RNE; inputs are squares, no NaN/Inf
    return (unsigned short)(u >> 16);
}

// async global->LDS, 16B per lane (m97 pattern; dest must be linear in lane order)
__device__ __forceinline__ void gload16(const unsigned short* g, unsigned short* l) {
    __builtin_amdgcn_global_load_lds(
        (const __attribute__((address_space(1))) unsigned int*)g,
        (__attribute__((address_space(3))) unsigned int*)l, 16, 0, 0);
}

// ---------------------------------------------------------------------------
// K1: B = A0*A0 elementwise -> bf16 row-major (Bbf) and bf16 transposed (BbfT)
// ---------------------------------------------------------------------------
__global__ void prep_kernel(const float* __restrict__ A0,
                            unsigned short* __restrict__ Bbf,
                            unsigned short* __restrict__ BbfT) {
    __shared__ float tile[32][33];
    const int tx = threadIdx.x, ty = threadIdx.y;
    const int I = blockIdx.y, J = blockIdx.x;
    #pragma unroll
    for (int rr = ty; rr < 32; rr += 8) {
        float a = A0[(size_t)(I * 32 + rr) * NN + J * 32 + tx];
        float s = a * a;
        tile[rr][tx] = s;
        Bbf[(size_t)(I * 32 + rr) * NN + J * 32 + tx] = f2bf(s);
    }
    __syncthreads();
    #pragma unroll
    for (int rr = ty; rr < 32; rr += 8) {
        BbfT[(size_t)(J * 32 + rr) * NN + I * 32 + tx] = f2bf(tile[tx][rr]);
    }
}

// ---------------------------------------------------------------------------
// K2: C2 = B * B  (bf16 MFMA, fp32 accum), global_load_lds staging (m97-style)
// 128x128 tile, 4 waves (2x2), each wave 64x64 = 4x4 fragments of 16x16x32.
// ---------------------------------------------------------------------------
__launch_bounds__(256, 2)
__global__ void gemm_kernel(const unsigned short* __restrict__ A,
                            const unsigned short* __restrict__ BT,
                            float* __restrict__ C) {
    __shared__ unsigned short lA[128 * 32];
    __shared__ unsigned short lB[128 * 32];
    const int tid  = threadIdx.x;
    const int lane = tid & 63;
    const int w    = tid >> 6;
    const int wr   = w >> 1, wc = w & 1;
    const int rowBase = blockIdx.y * 128;
    const int colBase = blockIdx.x * 128;
    const int lr = lane & 15;            // M/N index within fragment
    const int lk = (lane >> 4) * 8;      // K offset (elements)

    // staging geometry: 128x32 bf16 tile = 8KB = 2 issues x 256 lanes x 16B
    // byte off = tid*16 -> row = off>>6 (64B/row), col = (off&63)/2 elements
    const int srow  = tid >> 2;          // 0..63
    const int skcol = (tid & 3) * 8;
    const unsigned short* gA0 = A  + (size_t)(rowBase + srow) * NN + skcol;
    const unsigned short* gA1 = A  + (size_t)(rowBase + 64 + srow) * NN + skcol;
    const unsigned short* gB0 = BT + (size_t)(colBase + srow) * NN + skcol;
    const unsigned short* gB1 = BT + (size_t)(colBase + 64 + srow) * NN + skcol;
    unsigned short* dA0 = &lA[srow * 32 + skcol];
    unsigned short* dA1 = &lA[(64 + srow) * 32 + skcol];
    unsigned short* dB0 = &lB[srow * 32 + skcol];
    unsigned short* dB1 = &lB[(64 + srow) * 32 + skcol];

    f32x4 acc[4][4] = {};

    for (int k0 = 0; k0 < NN; k0 += 32) {
        gload16(gA0 + k0, dA0);
        gload16(gA1 + k0, dA1);
        gload16(gB0 + k0, dB0);
        gload16(gB1 + k0, dB1);
        __syncthreads();                 // drains vmcnt (incl. global_load_lds)

        short8 af[4], bfr[4];
        #pragma unroll
        for (int mi = 0; mi < 4; ++mi)
            af[mi] = *(const short8*)&lA[(wr * 64 + mi * 16 + lr) * 32 + lk];
        #pragma unroll
        for (int ni = 0; ni < 4; ++ni)
            bfr[ni] = *(const short8*)&lB[(wc * 64 + ni * 16 + lr) * 32 + lk];

        #pragma unroll
        for (int mi = 0; mi < 4; ++mi)
            #pragma unroll
            for (int ni = 0; ni < 4; ++ni)
                acc[mi][ni] = __builtin_amdgcn_mfma_f32_16x16x32_bf16(
                    af[mi], bfr[ni], acc[mi][ni], 0, 0, 0);
        __syncthreads();
    }

    // C/D layout: col = lane&15, row = (lane>>4)*4 + reg   [measured m89/m91]
    const int orow = (lane >> 4) * 4;
    const int ocol = lane & 15;
    #pragma unroll
    for (int mi = 0; mi < 4; ++mi)
        #pragma unroll
        for (int ni = 0; ni < 4; ++ni) {
            int gr = rowBase + wr * 64 + mi * 16 + orow;
            int gc = colBase + wc * 64 + ni * 16 + ocol;
            #pragma unroll
            for (int r = 0; r < 4; ++r)
                C[(size_t)(gr + r) * NN + gc] = acc[mi][ni][r];
        }
}

// ---------------------------------------------------------------------------
// K3: fused pair reduction over 64x64 tile-pairs (I<=J of 32 slabs):
//   t2 = <B,B^T>, t3 = <C2,B^T>, t4 = <C2,C2^T>  -> per-block partials
//   rs = C2*1 (rowsums), cs = C2^T*1 (colsums)   -> distributed float atomics
// ---------------------------------------------------------------------------
__global__ void pair_reduce_kernel(const float* __restrict__ A0,
                                   const float* __restrict__ C2,
                                   float* __restrict__ rs, float* __restrict__ cs,
                                   double* __restrict__ pt2,
                                   double* __restrict__ pt3,
                                   double* __restrict__ pt4) {
    __shared__ float aIJ[64][65], aJI[64][65], cIJ[64][65], cJI[64][65];
    __shared__ double wred[3][4];
    int b = blockIdx.x;
    int I = 0;
    while (b >= 32 - I) { b -= 32 - I; ++I; }   // upper-tri pair (I<=J)
    const int J   = I + b;
    const int tid = threadIdx.x;
    const int tx  = tid & 63;
    const int wv  = tid >> 6;
    const size_t rI = (size_t)I * 64, rJ = (size_t)J * 64;
    const bool diag = (I == J);

    // stage 4 tiles (float4 global reads, scalar LDS writes into padded rows)
    for (int idx = tid; idx < 1024; idx += 256) {
        const int row = idx >> 4, c4 = (idx & 15) << 2;
        f4 va = *(const f4*)&A0[(rI + row) * NN + rJ + c4];
        f4 vb = *(const f4*)&A0[(rJ + row) * NN + rI + c4];
        f4 vc = *(const f4*)&C2[(rI + row) * NN + rJ + c4];
        f4 vd = *(const f4*)&C2[(rJ + row) * NN + rI + c4];
        #pragma unroll
        for (int k = 0; k < 4; ++k) {
            aIJ[row][c4 + k] = va[k] * va[k];
            aJI[row][c4 + k] = vb[k] * vb[k];
            cIJ[row][c4 + k] = vc[k];
            cJI[row][c4 + k] = vd[k];
        }
    }
    __syncthreads();

    double t2 = 0, t3 = 0, t4 = 0;
    float csJacc = 0.f, rsJacc = 0.f;
    for (int rr = wv; rr < 64; rr += 4) {
        float bij = aIJ[rr][tx], bji = aJI[tx][rr];   // both 2-way banks = free
        float cij = cIJ[rr][tx], cji = cJI[tx][rr];
        if (diag) {
            t2 += (double)bij * bji;
            t3 += (double)cij * bji;
            t4 += (double)cij * cji;
        } else {
            t2 += 2.0 * ((double)bij * bji);
            t3 += (double)cij * bji + (double)cji * bij;
            t4 += 2.0 * ((double)cij * cji);
        }
        csJacc += cij;     // per-thread partial colsum of cIJ (col = rJ+tx)
        rsJacc += cji;     // per-thread partial rowsum of cJI (row = rJ+tx)
        // wave reductions: rowsum of cIJ row rr; colsum of cJI col rr
        float rsum = cij, csum = cji;
        #pragma unroll
        for (int s = 32; s > 0; s >>= 1) {
            rsum += __shfl_down(rsum, s, 64);
            csum += __shfl_down(csum, s, 64);
        }
        if (tx == 0) {
            atomicAdd(&rs[rI + rr], rsum);
            if (!diag) atomicAdd(&cs[rI + rr], csum);
        }
    }
    atomicAdd(&cs[rJ + tx], csJacc);
    if (!diag) atomicAdd(&rs[rJ + tx], rsJacc);

    // block partials for t2/t3/t4 (no contended global atomics)
    #pragma unroll
    for (int s = 32; s > 0; s >>= 1) {
        t2 += __shfl_down(t2, s, 64);
        t3 += __shfl_down(t3, s, 64);
        t4 += __shfl_down(t4, s, 64);
    }
    if (tx == 0) { wred[0][wv] = t2; wred[1][wv] = t3; wred[2][wv] = t4; }
    __syncthreads();
    if (tid == 0) {
        pt2[blockIdx.x] = wred[0][0] + wred[0][1] + wred[0][2] + wred[0][3];
        pt3[blockIdx.x] = wred[1][0] + wred[1][1] + wred[1][2] + wred[1][3];
        pt4[blockIdx.x] = wred[2][0] + wred[2][1] + wred[2][2] + wred[2][3];
    }
}

// ---------------------------------------------------------------------------
// K4: t1 = tr(B); lam^2 = (rs.cs)/(sum rs); h = t1 + t2/2 + t3/6 + t4/24 + tail
// ---------------------------------------------------------------------------
__global__ void finalize_kernel(const float* __restrict__ A0,
                                const float* __restrict__ rs,
                                const float* __restrict__ cs,
                                const double* __restrict__ pt2,
                                const double* __restrict__ pt3,
                                const double* __restrict__ pt4,
                                float* __restrict__ out) {
    __shared__ double red[256];
    const int t = threadIdx.x;
    double t2 = 0, t3 = 0, t4 = 0, t1 = 0, s2 = 0, s4 = 0;
    for (int i = t; i < 528; i += 256) { t2 += pt2[i]; t3 += pt3[i]; t4 += pt4[i]; }
    for (int i = t; i < NN; i += 256) {
        double d = A0[(size_t)i * NN + i];
        t1 += d * d;
        double r = rs[i];
        s2 += r; s4 += r * (double)cs[i];
    }
    double vals[6] = {t1, t2, t3, t4, s2, s4};
    double tot[6];
    #pragma unroll
    for (int v = 0; v < 6; ++v) {
        red[t] = vals[v]; __syncthreads();
        for (int s = 128; s > 0; s >>= 1) { if (t < s) red[t] += red[t + s]; __syncthreads(); }
        tot[v] = red[0]; __syncthreads();
    }
    if (t == 0) {
        double T1 = tot[0], T2 = tot[1], T3 = tot[2], T4 = tot[3];
        double lam2 = tot[5] / tot[4];
        double lam  = sqrt(lam2);
        double tail = exp(lam) - 1.0 - lam - lam2 * 0.5
                      - lam * lam2 * (1.0 / 6.0) - lam2 * lam2 * (1.0 / 24.0);
        out[0] = (float)(T1 + T2 * 0.5 + T3 * (1.0 / 6.0) + T4 * (1.0 / 24.0) + tail);
    }
}

// ---------------------------------------------------------------------------
extern "C" void kernel_launch(void* const* d_in, const int* in_sizes, int n_in,
                              void* d_out, int out_size, void* d_ws, size_t ws_size,
                              hipStream_t stream) {
    const float* A0 = (const float*)d_in[0];     // contemporaneous slice [2048,2048]
    char* ws = (char*)d_ws;
    unsigned short* Bbf  = (unsigned short*)(ws);                 //  8 MB bf16 B
    unsigned short* BbfT = (unsigned short*)(ws + 8388608);       //  8 MB bf16 B^T
    float*  C2   = (float*)(ws + 16777216);                       // 16 MB fp32 B^2
    float*  rs   = (float*)(ws + 33554432);                       //  8 KB rowsums
    float*  cs   = (float*)(ws + 33562624);                       //  8 KB colsums
    double* pt2  = (double*)(ws + 33570816);                      //  528 partials
    double* pt3  = (double*)(ws + 33575168);
    double* pt4  = (double*)(ws + 33579520);
    float*  out  = (float*)d_out;

    hipMemsetAsync(ws + 33554432, 0, 16384, stream);              // rs + cs
    prep_kernel<<<dim3(64, 64), dim3(32, 8), 0, stream>>>(A0, Bbf, BbfT);
    gemm_kernel<<<dim3(16, 16), 256, 0, stream>>>(Bbf, BbfT, C2);
    pair_reduce_kernel<<<528, 256, 0, stream>>>(A0, C2, rs, cs, pt2, pt3, pt4);
    finalize_kernel<<<1, 256, 0, stream>>>(A0, rs, cs, pt2, pt3, pt4, out);
}

// Round 4
// 156.937 us; speedup vs baseline: 1.5557x; 1.0794x over previous
//
#include <hip/hip_runtime.h>
#include <hip/hip_bf16.h>

#define NN 2048

typedef __attribute__((ext_vector_type(8))) short short8;
typedef __attribute__((ext_vector_type(4))) float f4;
typedef __attribute__((ext_vector_type(4))) float f32x4;
typedef __attribute__((ext_vector_type(4))) unsigned short us4;

__device__ __forceinline__ unsigned short f2bf(float f) {
    unsigned int u = __float_as_uint(f);
    u += 0x7fffu + ((u >> 16) & 1u);   // RNE; inputs are squares, no NaN/Inf
    return (unsigned short)(u >> 16);
}
__device__ __forceinline__ float bf2f(unsigned short h) {
    return __uint_as_float(((unsigned int)h) << 16);
}
__device__ __forceinline__ void gload16(const unsigned short* g, unsigned short* l) {
    __builtin_amdgcn_global_load_lds(
        (const __attribute__((address_space(1))) unsigned int*)g,
        (__attribute__((address_space(3))) unsigned int*)l, 16, 0, 0);
}
__device__ __forceinline__ void pair_decode(int b, int& I, int& J) {
    I = 0;
    while (b >= 32 - I) { b -= 32 - I; ++I; }
    J = I + b;
}

// ---------------------------------------------------------------------------
// K1: pair-structured prep: B = A0^2 -> Bbf + BbfT (both orientations), plus
//     t1 = tr(B) and t2 = <B, B^T> partials. A0 read exactly once.
// ---------------------------------------------------------------------------
__global__ void prep2_kernel(const float* __restrict__ A0,
                             unsigned short* __restrict__ Bbf,
                             unsigned short* __restrict__ BbfT,
                             double* __restrict__ pt1,
                             double* __restrict__ pt2) {
    __shared__ float sIJ[64][65], sJI[64][65];
    __shared__ double wred[2][4];
    int I, J; pair_decode(blockIdx.x, I, J);
    const bool diag = (I == J);
    const int tid = threadIdx.x;
    const int tx = tid & 63, wv = tid >> 6;
    const size_t rI = (size_t)I * 64, rJ = (size_t)J * 64;

    #pragma unroll
    for (int r0 = 0; r0 < 64; r0 += 16) {
        const int row = r0 + (tid >> 4), c4 = (tid & 15) * 4;
        f4 va = *(const f4*)&A0[(rI + row) * NN + rJ + c4];
        #pragma unroll
        for (int k = 0; k < 4; ++k) sIJ[row][c4 + k] = va[k] * va[k];
        if (!diag) {
            f4 vb = *(const f4*)&A0[(rJ + row) * NN + rI + c4];
            #pragma unroll
            for (int k = 0; k < 4; ++k) sJI[row][c4 + k] = vb[k] * vb[k];
        }
    }
    __syncthreads();

    double t1 = 0, t2 = 0;
    for (int rr = wv; rr < 64; rr += 4) {
        float sij  = sIJ[rr][tx];                       // B[rI+rr][rJ+tx]
        float sji  = diag ? sIJ[tx][rr] : sJI[tx][rr];  // B[rJ+tx][rI+rr]
        Bbf [(rI + rr) * NN + rJ + tx] = f2bf(sij);
        BbfT[(rJ + rr) * NN + rI + tx] = f2bf(sIJ[tx][rr]);
        if (!diag) {
            Bbf [(rJ + rr) * NN + rI + tx] = f2bf(sJI[rr][tx]);
            BbfT[(rI + rr) * NN + rJ + tx] = f2bf(sJI[tx][rr]);
            t2 += 2.0 * (double)sij * (double)sji;
        } else {
            t2 += (double)sij * (double)sji;
            if (rr == tx) t1 += sij;
        }
    }

    #pragma unroll
    for (int s = 32; s > 0; s >>= 1) {
        t1 += __shfl_down(t1, s, 64);
        t2 += __shfl_down(t2, s, 64);
    }
    if (tx == 0) { wred[0][wv] = t1; wred[1][wv] = t2; }
    __syncthreads();
    if (tid == 0) {
        pt1[blockIdx.x] = wred[0][0] + wred[0][1] + wred[0][2] + wred[0][3];
        pt2[blockIdx.x] = wred[1][0] + wred[1][1] + wred[1][2] + wred[1][3];
    }
}

// ---------------------------------------------------------------------------
// K2: C2 = B*B (bf16 MFMA). 128x64 tile, grid 512 (2 blocks/CU), BK=32,
//     double-buffered LDS w/ prefetch-before-compute. Epilogue: rs/cs fused.
// ---------------------------------------------------------------------------
__launch_bounds__(256, 2)
__global__ void gemm_kernel(const unsigned short* __restrict__ A,
                            const unsigned short* __restrict__ BT,
                            float* __restrict__ C,
                            float* __restrict__ rs,
                            float* __restrict__ cs) {
    __shared__ unsigned short lA[2][128 * 32];
    __shared__ unsigned short lB[2][64 * 32];
    const int tid  = threadIdx.x;
    const int lane = tid & 63;
    const int w    = tid >> 6;
    const int wr   = w >> 1, wc = w & 1;     // 2x2 waves over 128x64
    const int rowBase = blockIdx.y * 128;
    const int colBase = blockIdx.x * 64;
    const int lr = lane & 15;
    const int lk = (lane >> 4) * 8;

    // staging: A tile 128x32 (8KB, 2 issues), B tile 64x32 (4KB, 1 issue)
    const int srow = tid >> 2;               // 0..63, 64B rows
    const int scol = (tid & 3) * 8;
    const unsigned short* gA0 = A  + (size_t)(rowBase + srow) * NN + scol;
    const unsigned short* gA1 = A  + (size_t)(rowBase + 64 + srow) * NN + scol;
    const unsigned short* gB0 = BT + (size_t)(colBase + srow) * NN + scol;
    const int dA0 = srow * 32 + scol;
    const int dA1 = (64 + srow) * 32 + scol;

    f32x4 acc[4][2] = {};

    gload16(gA0, &lA[0][dA0]);
    gload16(gA1, &lA[0][dA1]);
    gload16(gB0, &lB[0][dA0]);
    __syncthreads();

    for (int t = 0; t < 64; ++t) {
        const int cur = t & 1;
        if (t < 63) {                        // prefetch next K-tile into buf^1
            const int k = (t + 1) * 32;
            gload16(gA0 + k, &lA[cur ^ 1][dA0]);
            gload16(gA1 + k, &lA[cur ^ 1][dA1]);
            gload16(gB0 + k, &lB[cur ^ 1][dA0]);
        }
        short8 af[4], bfr[2];
        #pragma unroll
        for (int mi = 0; mi < 4; ++mi)
            af[mi] = *(const short8*)&lA[cur][(wr * 64 + mi * 16 + lr) * 32 + lk];
        #pragma unroll
        for (int ni = 0; ni < 2; ++ni)
            bfr[ni] = *(const short8*)&lB[cur][(wc * 32 + ni * 16 + lr) * 32 + lk];
        #pragma unroll
        for (int mi = 0; mi < 4; ++mi)
            #pragma unroll
            for (int ni = 0; ni < 2; ++ni)
                acc[mi][ni] = __builtin_amdgcn_mfma_f32_16x16x32_bf16(
                    af[mi], bfr[ni], acc[mi][ni], 0, 0, 0);
        __syncthreads();                     // drains vmcnt -> buf^1 staged
    }

    // C/D layout: col = lane&15, row = (lane>>4)*4 + reg
    const int orow = (lane >> 4) * 4;
    const int ocol = lane & 15;
    float colp0 = 0.f, colp1 = 0.f;
    #pragma unroll
    for (int mi = 0; mi < 4; ++mi) {
        #pragma unroll
        for (int r = 0; r < 4; ++r) {
            const int gr = rowBase + wr * 64 + mi * 16 + orow + r;
            float v0 = acc[mi][0][r], v1 = acc[mi][1][r];
            C[(size_t)gr * NN + colBase + wc * 32 + ocol]      = v0;
            C[(size_t)gr * NN + colBase + wc * 32 + 16 + ocol] = v1;
            float rowp = v0 + v1;            // row-sum over wave's 32 cols
            rowp += __shfl_xor(rowp, 1, 64);
            rowp += __shfl_xor(rowp, 2, 64);
            rowp += __shfl_xor(rowp, 4, 64);
            rowp += __shfl_xor(rowp, 8, 64);
            if ((lane & 15) == 0) atomicAdd(&rs[gr], rowp);
            colp0 += v0; colp1 += v1;
        }
    }
    colp0 += __shfl_xor(colp0, 16, 64); colp0 += __shfl_xor(colp0, 32, 64);
    colp1 += __shfl_xor(colp1, 16, 64); colp1 += __shfl_xor(colp1, 32, 64);
    if (lane < 16) {
        atomicAdd(&cs[colBase + wc * 32 + ocol],      colp0);
        atomicAdd(&cs[colBase + wc * 32 + 16 + ocol], colp1);
    }
}

// ---------------------------------------------------------------------------
// K3: t3 = <C2, B^T>, t4 = <C2, C2^T> over 64x64 tile-pairs.
//     3 of 4 streams are direct coalesced reads; LDS only for the transpose.
// ---------------------------------------------------------------------------
__global__ void corr_kernel(const float* __restrict__ C2,
                            const unsigned short* __restrict__ BbfT,
                            double* __restrict__ pt3,
                            double* __restrict__ pt4) {
    __shared__ float cIJ[64][65], cJI[64][65];
    __shared__ double wred[2][4];
    int I, J; pair_decode(blockIdx.x, I, J);
    const bool diag = (I == J);
    const int tid = threadIdx.x;
    const int tx = tid & 63, wv = tid >> 6;
    const size_t rI = (size_t)I * 64, rJ = (size_t)J * 64;

    double t3 = 0;
    #pragma unroll
    for (int r0 = 0; r0 < 64; r0 += 16) {
        const int row = r0 + (tid >> 4), c4 = (tid & 15) * 4;
        f4  vc = *(const f4*)&C2[(rI + row) * NN + rJ + c4];
        us4 vb = *(const us4*)&BbfT[(rI + row) * NN + rJ + c4];  // = B_ji
        #pragma unroll
        for (int k = 0; k < 4; ++k) {
            cIJ[row][c4 + k] = vc[k];
            t3 += (double)vc[k] * (double)bf2f(vb[k]);
        }
        if (!diag) {
            f4  vd = *(const f4*)&C2[(rJ + row) * NN + rI + c4];
            us4 ve = *(const us4*)&BbfT[(rJ + row) * NN + rI + c4];
            #pragma unroll
            for (int k = 0; k < 4; ++k) {
                cJI[row][c4 + k] = vd[k];
                t3 += (double)vd[k] * (double)bf2f(ve[k]);
            }
        }
    }
    __syncthreads();

    double t4 = 0;
    for (int rr = wv; rr < 64; rr += 4) {
        float a = cIJ[rr][tx];
        float b = diag ? cIJ[tx][rr] : cJI[tx][rr];   // C2_ji (2-way bank, free)
        t4 += (double)a * (double)b;
    }
    if (!diag) t4 *= 2.0;

    #pragma unroll
    for (int s = 32; s > 0; s >>= 1) {
        t3 += __shfl_down(t3, s, 64);
        t4 += __shfl_down(t4, s, 64);
    }
    if (tx == 0) { wred[0][wv] = t3; wred[1][wv] = t4; }
    __syncthreads();
    if (tid == 0) {
        pt3[blockIdx.x] = wred[0][0] + wred[0][1] + wred[0][2] + wred[0][3];
        pt4[blockIdx.x] = wred[1][0] + wred[1][1] + wred[1][2] + wred[1][3];
    }
}

// ---------------------------------------------------------------------------
// K4: combine. lam^2 = (rs.cs)/sum(rs); h = t1 + t2/2 + t3/6 + t4/24 + tail
// ---------------------------------------------------------------------------
__global__ void finalize_kernel(const float* __restrict__ rs,
                                const float* __restrict__ cs,
                                const double* __restrict__ pt1,
                                const double* __restrict__ pt2,
                                const double* __restrict__ pt3,
                                const double* __restrict__ pt4,
                                float* __restrict__ out) {
    __shared__ double red[256];
    const int t = threadIdx.x;
    double t1 = 0, t2 = 0, t3 = 0, t4 = 0, s2 = 0, s4 = 0;
    for (int i = t; i < 528; i += 256) {
        t1 += pt1[i]; t2 += pt2[i]; t3 += pt3[i]; t4 += pt4[i];
    }
    for (int i = t; i < NN; i += 256) {
        double r = rs[i];
        s2 += r; s4 += r * (double)cs[i];
    }
    double vals[6] = {t1, t2, t3, t4, s2, s4};
    double tot[6];
    for (int v = 0; v < 6; ++v) {
        red[t] = vals[v]; __syncthreads();
        for (int s = 128; s > 0; s >>= 1) { if (t < s) red[t] += red[t + s]; __syncthreads(); }
        tot[v] = red[0]; __syncthreads();
    }
    if (t == 0) {
        double lam2 = tot[5] / tot[4];
        double lam  = sqrt(lam2);
        double tail = exp(lam) - 1.0 - lam - lam2 * 0.5
                      - lam * lam2 * (1.0 / 6.0) - lam2 * lam2 * (1.0 / 24.0);
        out[0] = (float)(tot[0] + tot[1] * 0.5 + tot[2] * (1.0 / 6.0)
                         + tot[3] * (1.0 / 24.0) + tail);
    }
}

// ---------------------------------------------------------------------------
extern "C" void kernel_launch(void* const* d_in, const int* in_sizes, int n_in,
                              void* d_out, int out_size, void* d_ws, size_t ws_size,
                              hipStream_t stream) {
    const float* A0 = (const float*)d_in[0];     // contemporaneous slice [2048,2048]
    char* ws = (char*)d_ws;
    unsigned short* Bbf  = (unsigned short*)(ws);                 //  8 MB
    unsigned short* BbfT = (unsigned short*)(ws + 8388608);       //  8 MB
    float*  C2   = (float*)(ws + 16777216);                       // 16 MB
    float*  rs   = (float*)(ws + 33554432);                       //  8 KB
    float*  cs   = (float*)(ws + 33562624);                       //  8 KB
    double* pt1  = (double*)(ws + 33570816);                      //  528 partials
    double* pt2  = (double*)(ws + 33579008);
    double* pt3  = (double*)(ws + 33587200);
    double* pt4  = (double*)(ws + 33595392);
    float*  out  = (float*)d_out;

    hipMemsetAsync(ws + 33554432, 0, 16384, stream);              // rs + cs
    prep2_kernel<<<528, 256, 0, stream>>>(A0, Bbf, BbfT, pt1, pt2);
    gemm_kernel<<<dim3(32, 16), 256, 0, stream>>>(Bbf, BbfT, C2, rs, cs);
    corr_kernel<<<528, 256, 0, stream>>>(C2, BbfT, pt3, pt4);
    finalize_kernel<<<1, 256, 0, stream>>>(rs, cs, pt1, pt2, pt3, pt4, out);
}

// Round 5
// 143.101 us; speedup vs baseline: 1.7061x; 1.0967x over previous
//
#include <hip/hip_runtime.h>
#include <hip/hip_bf16.h>

#define NN 2048
typedef unsigned short us;
typedef __attribute__((ext_vector_type(8))) short short8;
typedef __attribute__((ext_vector_type(4))) float f4;
typedef __attribute__((ext_vector_type(4))) float f32x4;
typedef __attribute__((ext_vector_type(8))) unsigned short us8;

__device__ __forceinline__ us f2bf(float f) {
    unsigned int u = __float_as_uint(f);
    u += 0x7fffu + ((u >> 16) & 1u);   // RNE; inputs tame, no NaN/Inf
    return (us)(u >> 16);
}
__device__ __forceinline__ float bf2f(us h) {
    return __uint_as_float(((unsigned int)h) << 16);
}
__device__ __forceinline__ void gload16(const us* g, us* l) {
    __builtin_amdgcn_global_load_lds(
        (const __attribute__((address_space(1))) unsigned int*)g,
        (__attribute__((address_space(3))) unsigned int*)l, 16, 0, 0);
}
__device__ __forceinline__ void pair_decode(int b, int& I, int& J) {
    I = 0;
    while (b >= 32 - I) { b -= 32 - I; ++I; }
    J = I + b;
}

// ---------------------------------------------------------------------------
// K1: pair prep. B = A0^2 -> Bbf + BbfT (us8-vectorized stores), t1, t2.
// ---------------------------------------------------------------------------
__global__ void prep_kernel(const float* __restrict__ A0,
                            us* __restrict__ Bbf, us* __restrict__ BbfT,
                            double* __restrict__ pt1, double* __restrict__ pt2) {
    __shared__ float sIJ[64][65], sJI[64][65];
    __shared__ double wred[2][4];
    int I, J; pair_decode(blockIdx.x, I, J);
    const bool diag = (I == J);
    const int tid = threadIdx.x, lane = tid & 63, wv = tid >> 6;
    const size_t rI = (size_t)I * 64, rJ = (size_t)J * 64;

    // phase A: f4 loads, square, us8 Bbf stores, fp32 LDS for transpose/t2
    #pragma unroll
    for (int u = tid; u < 512; u += 256) {
        const int row = u >> 3, c8 = (u & 7) * 8;
        f4 a0 = *(const f4*)&A0[(rI + row) * NN + rJ + c8];
        f4 a1 = *(const f4*)&A0[(rI + row) * NN + rJ + c8 + 4];
        us8 o;
        #pragma unroll
        for (int k = 0; k < 4; ++k) { float s = a0[k]*a0[k]; sIJ[row][c8+k] = s; o[k] = f2bf(s); }
        #pragma unroll
        for (int k = 0; k < 4; ++k) { float s = a1[k]*a1[k]; sIJ[row][c8+4+k] = s; o[4+k] = f2bf(s); }
        *(us8*)&Bbf[(rI + row) * NN + rJ + c8] = o;
        if (!diag) {
            f4 b0 = *(const f4*)&A0[(rJ + row) * NN + rI + c8];
            f4 b1 = *(const f4*)&A0[(rJ + row) * NN + rI + c8 + 4];
            us8 p;
            #pragma unroll
            for (int k = 0; k < 4; ++k) { float s = b0[k]*b0[k]; sJI[row][c8+k] = s; p[k] = f2bf(s); }
            #pragma unroll
            for (int k = 0; k < 4; ++k) { float s = b1[k]*b1[k]; sJI[row][c8+4+k] = s; p[4+k] = f2bf(s); }
            *(us8*)&Bbf[(rJ + row) * NN + rI + c8] = p;
        }
    }
    __syncthreads();

    // phase B: transposed us8 stores (lane-consecutive LDS reads, conflict-free)
    #pragma unroll
    for (int u = tid; u < 512; u += 256) {
        const int r = u & 63, c0 = (u >> 6) * 8;
        us8 o;
        #pragma unroll
        for (int k = 0; k < 8; ++k) o[k] = f2bf(sIJ[c0 + k][r]);
        *(us8*)&BbfT[(rJ + r) * NN + rI + c0] = o;     // B[rI+c][rJ+r] -> T
        if (!diag) {
            us8 p;
            #pragma unroll
            for (int k = 0; k < 8; ++k) p[k] = f2bf(sJI[c0 + k][r]);
            *(us8*)&BbfT[(rI + r) * NN + rJ + c0] = p;
        }
    }

    // t1 = tr(B) (diag tiles), t2 = <B, B^T>
    double t1 = 0, t2 = 0;
    for (int rr = wv; rr < 64; rr += 4) {
        float sij = sIJ[rr][lane];
        float sji = diag ? sIJ[lane][rr] : sJI[lane][rr];
        if (diag) { t2 += (double)sij * sji; if (rr == lane) t1 += sij; }
        else       t2 += 2.0 * (double)sij * sji;
    }
    #pragma unroll
    for (int s = 32; s > 0; s >>= 1) {
        t1 += __shfl_down(t1, s, 64);
        t2 += __shfl_down(t2, s, 64);
    }
    if (lane == 0) { wred[0][wv] = t1; wred[1][wv] = t2; }
    __syncthreads();
    if (tid == 0) {
        pt1[blockIdx.x] = wred[0][0] + wred[0][1] + wred[0][2] + wred[0][3];
        pt2[blockIdx.x] = wred[1][0] + wred[1][1] + wred[1][2] + wred[1][3];
    }
}

// ---------------------------------------------------------------------------
// K2: split-K GEMM. z-half computes 128x128 tile over K=1024, BK=32, dbuf.
//     Writes bf16 half c2h[z]; fused rs/cs (exact fp32) via atomics.
// ---------------------------------------------------------------------------
__launch_bounds__(256, 2)
__global__ void gemm_kernel(const us* __restrict__ A, const us* __restrict__ BT,
                            us* __restrict__ c2a, us* __restrict__ c2b,
                            float* __restrict__ rs, float* __restrict__ cs) {
    __shared__ us lA[2][4096];
    __shared__ us lB[2][4096];
    const int tid  = threadIdx.x;
    const int lane = tid & 63;
    const int w    = tid >> 6;
    const int wr   = w >> 1, wc = w & 1;     // 2x2 waves over 128x128
    const int rowBase = blockIdx.y * 128;
    const int colBase = blockIdx.x * 128;
    const int kbase   = blockIdx.z * 1024;
    us* __restrict__ C = blockIdx.z ? c2b : c2a;
    const int lr = lane & 15;
    const int lk = (lane >> 4) * 8;

    const int srow = tid >> 2;               // 0..63, 64B rows
    const int scol = (tid & 3) * 8;
    const us* gA0 = A  + (size_t)(rowBase + srow) * NN + kbase + scol;
    const us* gA1 = A  + (size_t)(rowBase + 64 + srow) * NN + kbase + scol;
    const us* gB0 = BT + (size_t)(colBase + srow) * NN + kbase + scol;
    const us* gB1 = BT + (size_t)(colBase + 64 + srow) * NN + kbase + scol;
    const int d0 = srow * 32 + scol;
    const int d1 = (64 + srow) * 32 + scol;

    f32x4 acc[4][4] = {};

    gload16(gA0, &lA[0][d0]);
    gload16(gA1, &lA[0][d1]);
    gload16(gB0, &lB[0][d0]);
    gload16(gB1, &lB[0][d1]);
    __syncthreads();

    for (int t = 0; t < 32; ++t) {
        const int cur = t & 1;
        if (t < 31) {                        // prefetch t+1 into buf^1
            const int k = (t + 1) * 32;
            gload16(gA0 + k, &lA[cur ^ 1][d0]);
            gload16(gA1 + k, &lA[cur ^ 1][d1]);
            gload16(gB0 + k, &lB[cur ^ 1][d0]);
            gload16(gB1 + k, &lB[cur ^ 1][d1]);
        }
        short8 af[4], bfr[4];
        #pragma unroll
        for (int mi = 0; mi < 4; ++mi)
            af[mi] = *(const short8*)&lA[cur][(wr * 64 + mi * 16 + lr) * 32 + lk];
        #pragma unroll
        for (int ni = 0; ni < 4; ++ni)
            bfr[ni] = *(const short8*)&lB[cur][(wc * 64 + ni * 16 + lr) * 32 + lk];
        #pragma unroll
        for (int mi = 0; mi < 4; ++mi)
            #pragma unroll
            for (int ni = 0; ni < 4; ++ni)
                acc[mi][ni] = __builtin_amdgcn_mfma_f32_16x16x32_bf16(
                    af[mi], bfr[ni], acc[mi][ni], 0, 0, 0);
        __syncthreads();                     // drains prefetch; buf^1 ready
    }

    // epilogue: bf16 C-half write + exact rs/cs partial sums
    const int orow = (lane >> 4) * 4;
    const int ocol = lane & 15;
    float colp[4] = {0.f, 0.f, 0.f, 0.f};
    #pragma unroll
    for (int mi = 0; mi < 4; ++mi) {
        #pragma unroll
        for (int r = 0; r < 4; ++r) {
            const int gr = rowBase + wr * 64 + mi * 16 + orow + r;
            float rowp = 0.f;
            #pragma unroll
            for (int ni = 0; ni < 4; ++ni) {
                float v = acc[mi][ni][r];
                C[(size_t)gr * NN + colBase + wc * 64 + ni * 16 + ocol] = f2bf(v);
                rowp += v;
                colp[ni] += v;
            }
            rowp += __shfl_xor(rowp, 1, 64);
            rowp += __shfl_xor(rowp, 2, 64);
            rowp += __shfl_xor(rowp, 4, 64);
            rowp += __shfl_xor(rowp, 8, 64);
            if ((lane & 15) == 0) atomicAdd(&rs[gr], rowp);
        }
    }
    #pragma unroll
    for (int ni = 0; ni < 4; ++ni) {
        colp[ni] += __shfl_xor(colp[ni], 16, 64);
        colp[ni] += __shfl_xor(colp[ni], 32, 64);
        if (lane < 16) atomicAdd(&cs[colBase + wc * 64 + ni * 16 + ocol], colp[ni]);
    }
}

// ---------------------------------------------------------------------------
// K3: t3 = <C2, B^T> (coalesced elementwise: BbfT[i][j] = B_ji),
//     t4 = <C2, C2^T> via pair-tile LDS transpose. C2 = c2a + c2b.
// ---------------------------------------------------------------------------
__global__ void corr_kernel(const us* __restrict__ c2a, const us* __restrict__ c2b,
                            const us* __restrict__ BbfT,
                            double* __restrict__ pt3, double* __restrict__ pt4) {
    __shared__ float cIJ[64][65], cJI[64][65];
    __shared__ double wred[2][4];
    int I, J; pair_decode(blockIdx.x, I, J);
    const bool diag = (I == J);
    const int tid = threadIdx.x, lane = tid & 63, wv = tid >> 6;
    const size_t rI = (size_t)I * 64, rJ = (size_t)J * 64;

    double t3 = 0;
    #pragma unroll
    for (int u = tid; u < 512; u += 256) {
        const int row = u >> 3, c8 = (u & 7) * 8;
        const size_t off = (rI + row) * NN + rJ + c8;
        us8 va = *(const us8*)&c2a[off];
        us8 vb = *(const us8*)&c2b[off];
        us8 vt = *(const us8*)&BbfT[off];
        #pragma unroll
        for (int k = 0; k < 8; ++k) {
            float c = bf2f(va[k]) + bf2f(vb[k]);
            cIJ[row][c8 + k] = c;
            t3 += (double)(c * bf2f(vt[k]));
        }
        if (!diag) {
            const size_t off2 = (rJ + row) * NN + rI + c8;
            us8 wa = *(const us8*)&c2a[off2];
            us8 wb = *(const us8*)&c2b[off2];
            us8 wt = *(const us8*)&BbfT[off2];
            #pragma unroll
            for (int k = 0; k < 8; ++k) {
                float c = bf2f(wa[k]) + bf2f(wb[k]);
                cJI[row][c8 + k] = c;
                t3 += (double)(c * bf2f(wt[k]));
            }
        }
    }
    __syncthreads();

    double t4 = 0;
    for (int rr = wv; rr < 64; rr += 4) {
        float a = cIJ[rr][lane];
        float b = diag ? cIJ[lane][rr] : cJI[lane][rr];
        t4 += (double)a * b;
    }
    if (!diag) t4 *= 2.0;

    #pragma unroll
    for (int s = 32; s > 0; s >>= 1) {
        t3 += __shfl_down(t3, s, 64);
        t4 += __shfl_down(t4, s, 64);
    }
    if (lane == 0) { wred[0][wv] = t3; wred[1][wv] = t4; }
    __syncthreads();
    if (tid == 0) {
        pt3[blockIdx.x] = wred[0][0] + wred[0][1] + wred[0][2] + wred[0][3];
        pt4[blockIdx.x] = wred[1][0] + wred[1][1] + wred[1][2] + wred[1][3];
    }
}

// ---------------------------------------------------------------------------
// K4: combine. lam^2 = (rs.cs)/sum(rs); h = t1 + t2/2 + t3/6 + t4/24 + tail
// ---------------------------------------------------------------------------
__global__ void finalize_kernel(const float* __restrict__ rs,
                                const float* __restrict__ cs,
                                const double* __restrict__ pt1,
                                const double* __restrict__ pt2,
                                const double* __restrict__ pt3,
                                const double* __restrict__ pt4,
                                float* __restrict__ out) {
    __shared__ double red[256];
    const int t = threadIdx.x;
    double t1 = 0, t2 = 0, t3 = 0, t4 = 0, s2 = 0, s4 = 0;
    for (int i = t; i < 528; i += 256) {
        t1 += pt1[i]; t2 += pt2[i]; t3 += pt3[i]; t4 += pt4[i];
    }
    for (int i = t; i < NN; i += 256) {
        double r = rs[i];
        s2 += r; s4 += r * (double)cs[i];
    }
    double vals[6] = {t1, t2, t3, t4, s2, s4};
    double tot[6];
    for (int v = 0; v < 6; ++v) {
        red[t] = vals[v]; __syncthreads();
        for (int s = 128; s > 0; s >>= 1) { if (t < s) red[t] += red[t + s]; __syncthreads(); }
        tot[v] = red[0]; __syncthreads();
    }
    if (t == 0) {
        double lam2 = tot[5] / tot[4];
        double lam  = sqrt(lam2);
        double tail = exp(lam) - 1.0 - lam - lam2 * 0.5
                      - lam * lam2 * (1.0 / 6.0) - lam2 * lam2 * (1.0 / 24.0);
        out[0] = (float)(tot[0] + tot[1] * 0.5 + tot[2] * (1.0 / 6.0)
                         + tot[3] * (1.0 / 24.0) + tail);
    }
}

// ---------------------------------------------------------------------------
extern "C" void kernel_launch(void* const* d_in, const int* in_sizes, int n_in,
                              void* d_out, int out_size, void* d_ws, size_t ws_size,
                              hipStream_t stream) {
    const float* A0 = (const float*)d_in[0];     // contemporaneous slice [2048,2048]
    char* ws = (char*)d_ws;
    us*     Bbf  = (us*)(ws);                    //  8 MB bf16 B
    us*     BbfT = (us*)(ws + 8388608);          //  8 MB bf16 B^T
    us*     c2a  = (us*)(ws + 16777216);         //  8 MB bf16 B^2 half (K 0..1023)
    us*     c2b  = (us*)(ws + 25165824);         //  8 MB bf16 B^2 half (K 1024..2047)
    float*  rs   = (float*)(ws + 33554432);      //  8 KB rowsums of B^2
    float*  cs   = (float*)(ws + 33562624);      //  8 KB colsums of B^2
    double* pt1  = (double*)(ws + 33570816);     //  528 partials each
    double* pt2  = (double*)(ws + 33579008);
    double* pt3  = (double*)(ws + 33587200);
    double* pt4  = (double*)(ws + 33595392);
    float*  out  = (float*)d_out;

    hipMemsetAsync(ws + 33554432, 0, 16384, stream);   // rs + cs
    prep_kernel<<<528, 256, 0, stream>>>(A0, Bbf, BbfT, pt1, pt2);
    gemm_kernel<<<dim3(16, 16, 2), 256, 0, stream>>>(Bbf, BbfT, c2a, c2b, rs, cs);
    corr_kernel<<<528, 256, 0, stream>>>(c2a, c2b, BbfT, pt3, pt4);
    finalize_kernel<<<1, 256, 0, stream>>>(rs, cs, pt1, pt2, pt3, pt4, out);
}

// Round 6
// 139.502 us; speedup vs baseline: 1.7502x; 1.0258x over previous
//
#include <hip/hip_runtime.h>
#include <hip/hip_bf16.h>

#define NN 2048
typedef unsigned short us;
typedef __attribute__((ext_vector_type(8))) short short8;
typedef __attribute__((ext_vector_type(4))) float f4;
typedef __attribute__((ext_vector_type(4))) float f32x4;
typedef __attribute__((ext_vector_type(8))) unsigned short us8;

__device__ __forceinline__ us f2bf(float f) {
    unsigned int u = __float_as_uint(f);
    u += 0x7fffu + ((u >> 16) & 1u);   // RNE
    return (us)(u >> 16);
}
__device__ __forceinline__ float bf2f(us h) {
    return __uint_as_float(((unsigned int)h) << 16);
}
__device__ __forceinline__ void gload16(const us* g, us* l) {
    __builtin_amdgcn_global_load_lds(
        (const __attribute__((address_space(1))) unsigned int*)g,
        (__attribute__((address_space(3))) unsigned int*)l, 16, 0, 0);
}

// ---------------------------------------------------------------------------
// K1: prep. Block (I,J) reads A0 tile(I,J) once, writes Bbf tile(I,J) and
//     BbfT tile(J,I) (via LDS transpose, COALESCED us8 rows). Diag blocks
//     compute t1 and zero rs/cs.
// ---------------------------------------------------------------------------
__global__ void prep_kernel(const float* __restrict__ A0,
                            us* __restrict__ Bbf, us* __restrict__ BbfT,
                            float* __restrict__ rs, float* __restrict__ cs,
                            double* __restrict__ pt1) {
    __shared__ float sq[64][65];
    const int I = blockIdx.y, J = blockIdx.x;
    const int tid = threadIdx.x, lane = tid & 63, wv = tid >> 6;
    const size_t rI = (size_t)I * 64, rJ = (size_t)J * 64;

    // phase A: load f4x2, square, us8 store Bbf(I,J), fp32 LDS
    #pragma unroll
    for (int u = tid; u < 512; u += 256) {
        const int row = u >> 3, c8 = (u & 7) * 8;
        f4 a0 = *(const f4*)&A0[(rI + row) * NN + rJ + c8];
        f4 a1 = *(const f4*)&A0[(rI + row) * NN + rJ + c8 + 4];
        us8 o;
        #pragma unroll
        for (int k = 0; k < 4; ++k) { float s = a0[k] * a0[k]; sq[row][c8 + k] = s; o[k] = f2bf(s); }
        #pragma unroll
        for (int k = 0; k < 4; ++k) { float s = a1[k] * a1[k]; sq[row][c8 + 4 + k] = s; o[4 + k] = f2bf(s); }
        *(us8*)&Bbf[(rI + row) * NN + rJ + c8] = o;
    }
    __syncthreads();

    // phase B: BbfT tile(J,I): BbfT[rJ+r][rI+c] = B[rI+c][rJ+r] = sq[c][r]
    // r = u>>3 -> 8 lanes per output row (128B contiguous) = coalesced
    #pragma unroll
    for (int u = tid; u < 512; u += 256) {
        const int r = u >> 3, c0 = (u & 7) * 8;
        us8 o;
        #pragma unroll
        for (int k = 0; k < 8; ++k) o[k] = f2bf(sq[c0 + k][r]);   // 2-way bank, free
        *(us8*)&BbfT[(rJ + r) * NN + rI + c0] = o;
    }

    if (I == J) {
        if (tid < 64) { rs[rI + tid] = 0.f; cs[rI + tid] = 0.f; }
        if (wv == 0) {                      // t1 partial from diag of sq
            double t1 = sq[lane][lane];
            #pragma unroll
            for (int s = 32; s > 0; s >>= 1) t1 += __shfl_down(t1, s, 64);
            if (lane == 0) pt1[I] = t1;
        }
    }
}

// ---------------------------------------------------------------------------
// K2: split-K GEMM (unchanged from round 5). z-half: 128x128 tile over K=1024,
//     BK=32 dbuf, bf16 half outputs, fused exact fp32 rs/cs.
// ---------------------------------------------------------------------------
__launch_bounds__(256, 2)
__global__ void gemm_kernel(const us* __restrict__ A, const us* __restrict__ BT,
                            us* __restrict__ c2a, us* __restrict__ c2b,
                            float* __restrict__ rs, float* __restrict__ cs) {
    __shared__ us lA[2][4096];
    __shared__ us lB[2][4096];
    const int tid  = threadIdx.x;
    const int lane = tid & 63;
    const int w    = tid >> 6;
    const int wr   = w >> 1, wc = w & 1;
    const int rowBase = blockIdx.y * 128;
    const int colBase = blockIdx.x * 128;
    const int kbase   = blockIdx.z * 1024;
    us* __restrict__ C = blockIdx.z ? c2b : c2a;
    const int lr = lane & 15;
    const int lk = (lane >> 4) * 8;

    const int srow = tid >> 2;
    const int scol = (tid & 3) * 8;
    const us* gA0 = A  + (size_t)(rowBase + srow) * NN + kbase + scol;
    const us* gA1 = A  + (size_t)(rowBase + 64 + srow) * NN + kbase + scol;
    const us* gB0 = BT + (size_t)(colBase + srow) * NN + kbase + scol;
    const us* gB1 = BT + (size_t)(colBase + 64 + srow) * NN + kbase + scol;
    const int d0 = srow * 32 + scol;
    const int d1 = (64 + srow) * 32 + scol;

    f32x4 acc[4][4] = {};

    gload16(gA0, &lA[0][d0]);
    gload16(gA1, &lA[0][d1]);
    gload16(gB0, &lB[0][d0]);
    gload16(gB1, &lB[0][d1]);
    __syncthreads();

    for (int t = 0; t < 32; ++t) {
        const int cur = t & 1;
        if (t < 31) {
            const int k = (t + 1) * 32;
            gload16(gA0 + k, &lA[cur ^ 1][d0]);
            gload16(gA1 + k, &lA[cur ^ 1][d1]);
            gload16(gB0 + k, &lB[cur ^ 1][d0]);
            gload16(gB1 + k, &lB[cur ^ 1][d1]);
        }
        short8 af[4], bfr[4];
        #pragma unroll
        for (int mi = 0; mi < 4; ++mi)
            af[mi] = *(const short8*)&lA[cur][(wr * 64 + mi * 16 + lr) * 32 + lk];
        #pragma unroll
        for (int ni = 0; ni < 4; ++ni)
            bfr[ni] = *(const short8*)&lB[cur][(wc * 64 + ni * 16 + lr) * 32 + lk];
        #pragma unroll
        for (int mi = 0; mi < 4; ++mi)
            #pragma unroll
            for (int ni = 0; ni < 4; ++ni)
                acc[mi][ni] = __builtin_amdgcn_mfma_f32_16x16x32_bf16(
                    af[mi], bfr[ni], acc[mi][ni], 0, 0, 0);
        __syncthreads();
    }

    const int orow = (lane >> 4) * 4;
    const int ocol = lane & 15;
    float colp[4] = {0.f, 0.f, 0.f, 0.f};
    #pragma unroll
    for (int mi = 0; mi < 4; ++mi) {
        #pragma unroll
        for (int r = 0; r < 4; ++r) {
            const int gr = rowBase + wr * 64 + mi * 16 + orow + r;
            float rowp = 0.f;
            #pragma unroll
            for (int ni = 0; ni < 4; ++ni) {
                float v = acc[mi][ni][r];
                C[(size_t)gr * NN + colBase + wc * 64 + ni * 16 + ocol] = f2bf(v);
                rowp += v;
                colp[ni] += v;
            }
            rowp += __shfl_xor(rowp, 1, 64);
            rowp += __shfl_xor(rowp, 2, 64);
            rowp += __shfl_xor(rowp, 4, 64);
            rowp += __shfl_xor(rowp, 8, 64);
            if ((lane & 15) == 0) atomicAdd(&rs[gr], rowp);
        }
    }
    #pragma unroll
    for (int ni = 0; ni < 4; ++ni) {
        colp[ni] += __shfl_xor(colp[ni], 16, 64);
        colp[ni] += __shfl_xor(colp[ni], 32, 64);
        if (lane < 16) atomicAdd(&cs[colBase + wc * 64 + ni * 16 + ocol], colp[ni]);
    }
}

// ---------------------------------------------------------------------------
// K3: corr. Block (I,J): t2 = <Bbf,BbfT>, t3 = <C2,BbfT> (both elementwise,
//     coalesced), t4 = <C2(I,J), C2(J,I)^T> via one LDS transpose tile.
// ---------------------------------------------------------------------------
__global__ void corr_kernel(const us* __restrict__ c2a, const us* __restrict__ c2b,
                            const us* __restrict__ Bbf, const us* __restrict__ BbfT,
                            double* __restrict__ pt2, double* __restrict__ pt3,
                            double* __restrict__ pt4) {
    __shared__ float cT[64][65];       // C2 tile (J,I)
    __shared__ double wred[3][4];
    const int I = blockIdx.y, J = blockIdx.x;
    const int tid = threadIdx.x, lane = tid & 63, wv = tid >> 6;
    const size_t rI = (size_t)I * 64, rJ = (size_t)J * 64;

    double t2 = 0, t3 = 0;
    float myC[2][8];                   // this thread's C2(I,J) values (static idx)
    #pragma unroll
    for (int ph = 0; ph < 2; ++ph) {
        const int u = tid + ph * 256;
        const int row = u >> 3, c8 = (u & 7) * 8;
        const size_t off  = (rI + row) * NN + rJ + c8;
        const size_t off2 = (rJ + row) * NN + rI + c8;
        us8 va = *(const us8*)&c2a[off];
        us8 vb = *(const us8*)&c2b[off];
        us8 vt = *(const us8*)&BbfT[off];
        us8 vf = *(const us8*)&Bbf[off];
        us8 wa = *(const us8*)&c2a[off2];
        us8 wb = *(const us8*)&c2b[off2];
        #pragma unroll
        for (int k = 0; k < 8; ++k) {
            float c = bf2f(va[k]) + bf2f(vb[k]);
            myC[ph][k] = c;
            t3 += (double)(c * bf2f(vt[k]));
            t2 += (double)(bf2f(vf[k]) * bf2f(vt[k]));
            cT[row][c8 + k] = bf2f(wa[k]) + bf2f(wb[k]);
        }
    }
    __syncthreads();

    double t4 = 0;
    #pragma unroll
    for (int ph = 0; ph < 2; ++ph) {
        const int u = tid + ph * 256;
        const int row = u >> 3, c8 = (u & 7) * 8;
        #pragma unroll
        for (int k = 0; k < 8; ++k)
            t4 += (double)(myC[ph][k] * cT[c8 + k][row]);   // 2-way bank, free
    }

    #pragma unroll
    for (int s = 32; s > 0; s >>= 1) {
        t2 += __shfl_down(t2, s, 64);
        t3 += __shfl_down(t3, s, 64);
        t4 += __shfl_down(t4, s, 64);
    }
    if (lane == 0) { wred[0][wv] = t2; wred[1][wv] = t3; wred[2][wv] = t4; }
    __syncthreads();
    if (tid == 0) {
        const int b = blockIdx.y * 32 + blockIdx.x;
        pt2[b] = wred[0][0] + wred[0][1] + wred[0][2] + wred[0][3];
        pt3[b] = wred[1][0] + wred[1][1] + wred[1][2] + wred[1][3];
        pt4[b] = wred[2][0] + wred[2][1] + wred[2][2] + wred[2][3];
    }
}

// ---------------------------------------------------------------------------
// K4: combine. lam^2 = (rs.cs)/sum(rs); h = t1 + t2/2 + t3/6 + t4/24 + tail
// ---------------------------------------------------------------------------
__global__ void finalize_kernel(const float* __restrict__ rs,
                                const float* __restrict__ cs,
                                const double* __restrict__ pt1,
                                const double* __restrict__ pt2,
                                const double* __restrict__ pt3,
                                const double* __restrict__ pt4,
                                float* __restrict__ out) {
    __shared__ double red[256];
    const int t = threadIdx.x;
    double t1 = 0, t2 = 0, t3 = 0, t4 = 0, s2 = 0, s4 = 0;
    if (t < 32) t1 = pt1[t];
    for (int i = t; i < 1024; i += 256) { t2 += pt2[i]; t3 += pt3[i]; t4 += pt4[i]; }
    for (int i = t; i < NN; i += 256) {
        double r = rs[i];
        s2 += r; s4 += r * (double)cs[i];
    }
    double vals[6] = {t1, t2, t3, t4, s2, s4};
    double tot[6];
    for (int v = 0; v < 6; ++v) {
        red[t] = vals[v]; __syncthreads();
        for (int s = 128; s > 0; s >>= 1) { if (t < s) red[t] += red[t + s]; __syncthreads(); }
        tot[v] = red[0]; __syncthreads();
    }
    if (t == 0) {
        double lam2 = tot[5] / tot[4];
        double lam  = sqrt(lam2);
        double tail = exp(lam) - 1.0 - lam - lam2 * 0.5
                      - lam * lam2 * (1.0 / 6.0) - lam2 * lam2 * (1.0 / 24.0);
        out[0] = (float)(tot[0] + tot[1] * 0.5 + tot[2] * (1.0 / 6.0)
                         + tot[3] * (1.0 / 24.0) + tail);
    }
}

// ---------------------------------------------------------------------------
extern "C" void kernel_launch(void* const* d_in, const int* in_sizes, int n_in,
                              void* d_out, int out_size, void* d_ws, size_t ws_size,
                              hipStream_t stream) {
    const float* A0 = (const float*)d_in[0];     // contemporaneous slice [2048,2048]
    char* ws = (char*)d_ws;
    us*     Bbf  = (us*)(ws);                    //  8 MB bf16 B
    us*     BbfT = (us*)(ws + 8388608);          //  8 MB bf16 B^T
    us*     c2a  = (us*)(ws + 16777216);         //  8 MB bf16 B^2 (K 0..1023)
    us*     c2b  = (us*)(ws + 25165824);         //  8 MB bf16 B^2 (K 1024..2047)
    float*  rs   = (float*)(ws + 33554432);      //  8 KB rowsums of B^2
    float*  cs   = (float*)(ws + 33562624);      //  8 KB colsums of B^2
    double* pt1  = (double*)(ws + 33570816);     //  32 partials (t1)
    double* pt2  = (double*)(ws + 33571328);     //  1024 partials each
    double* pt3  = (double*)(ws + 33579520);
    double* pt4  = (double*)(ws + 33587712);
    float*  out  = (float*)d_out;

    prep_kernel<<<dim3(32, 32), 256, 0, stream>>>(A0, Bbf, BbfT, rs, cs, pt1);
    gemm_kernel<<<dim3(16, 16, 2), 256, 0, stream>>>(Bbf, BbfT, c2a, c2b, rs, cs);
    corr_kernel<<<dim3(32, 32), 256, 0, stream>>>(c2a, c2b, Bbf, BbfT, pt2, pt3, pt4);
    finalize_kernel<<<1, 256, 0, stream>>>(rs, cs, pt1, pt2, pt3, pt4, out);
}